// Round 2
// baseline (415.873 us; speedup 1.0000x reference)
//
#include <hip/hip_runtime.h>

// Problem constants (match reference)
#define NPTS_C 32            // channels
#define NTAPS 27             // 3x3x3
#define KEY_WORDS (1u << 20) // 2^25 keys / 32 bits
#define SCAN_BLOCKS 4096     // KEY_WORDS / 256

__device__ __forceinline__ unsigned make_key(int b, int x, int y, int z) {
    // ((b*256 + x)*256 + y)*256 + z ; b in {0,1}, x/y/z in [0,256)
    return ((((unsigned)b << 8 | (unsigned)x) << 8 | (unsigned)y) << 8) | (unsigned)z;
}

// 1) scatter occupancy bits
__global__ void k_scatter_bits(const int* __restrict__ coords, unsigned* __restrict__ bitmask, int n) {
    int i = blockIdx.x * blockDim.x + threadIdx.x;
    if (i >= n) return;
    int b = coords[4 * i + 0], x = coords[4 * i + 1], y = coords[4 * i + 2], z = coords[4 * i + 3];
    unsigned key = make_key(b, x, y, z);
    atomicOr(&bitmask[key >> 5], 1u << (key & 31u));
}

// 2) per-block (256 words) popcount sums
__global__ void k_popc_sums(const unsigned* __restrict__ bitmask, unsigned* __restrict__ blockSums) {
    __shared__ unsigned s[256];
    unsigned w = blockIdx.x * 256 + threadIdx.x;
    s[threadIdx.x] = __popc(bitmask[w]);
    __syncthreads();
    for (int off = 128; off > 0; off >>= 1) {
        if ((int)threadIdx.x < off) s[threadIdx.x] += s[threadIdx.x + off];
        __syncthreads();
    }
    if (threadIdx.x == 0) blockSums[blockIdx.x] = s[0];
}

// 3) exclusive scan of 4096 block sums, single block of 256 threads x 16 elems
__global__ void k_scan_sums(const unsigned* __restrict__ blockSums, unsigned* __restrict__ blockOffsets) {
    __shared__ unsigned s[256];
    unsigned local[16];
    unsigned sum = 0;
    int base = threadIdx.x * 16;
    for (int i = 0; i < 16; i++) { local[i] = blockSums[base + i]; sum += local[i]; }
    s[threadIdx.x] = sum;
    __syncthreads();
    // Hillis-Steele inclusive scan over 256
    for (int off = 1; off < 256; off <<= 1) {
        unsigned v = ((int)threadIdx.x >= off) ? s[threadIdx.x - off] : 0u;
        __syncthreads();
        s[threadIdx.x] += v;
        __syncthreads();
    }
    unsigned excl = (threadIdx.x == 0) ? 0u : s[threadIdx.x - 1];
    for (int i = 0; i < 16; i++) { blockOffsets[base + i] = excl; excl += local[i]; }
}

// 4) per-word exclusive prefix of popcounts
__global__ void k_word_prefix(const unsigned* __restrict__ bitmask, const unsigned* __restrict__ blockOffsets,
                              unsigned* __restrict__ wordPrefix) {
    __shared__ unsigned s[256];
    unsigned w = blockIdx.x * 256 + threadIdx.x;
    unsigned p = __popc(bitmask[w]);
    s[threadIdx.x] = p;
    __syncthreads();
    for (int off = 1; off < 256; off <<= 1) {
        unsigned v = ((int)threadIdx.x >= off) ? s[threadIdx.x - off] : 0u;
        __syncthreads();
        s[threadIdx.x] += v;
        __syncthreads();
    }
    wordPrefix[w] = blockOffsets[blockIdx.x] + (s[threadIdx.x] - p); // exclusive
}

__device__ __forceinline__ unsigned rank_of(unsigned key, const unsigned* bitmask, const unsigned* wordPrefix) {
    unsigned word = key >> 5, bit = key & 31u;
    return wordPrefix[word] + __popc(bitmask[word] & ((1u << bit) - 1u));
}

// 5) scatter original index + coords into sorted order.
// NOTE: d_out is read back as float32 for BOTH tuple outputs — coords must be
// written as float VALUES, not int bit patterns.
__global__ void k_scatter_rank(const int* __restrict__ coords, const unsigned* __restrict__ bitmask,
                               const unsigned* __restrict__ wordPrefix, int* __restrict__ origOf,
                               float* __restrict__ outCoordsF, int* __restrict__ sortedCoordsI, int n) {
    int i = blockIdx.x * blockDim.x + threadIdx.x;
    if (i >= n) return;
    int b = coords[4 * i + 0], x = coords[4 * i + 1], y = coords[4 * i + 2], z = coords[4 * i + 3];
    unsigned key = make_key(b, x, y, z);
    unsigned r = rank_of(key, bitmask, wordPrefix);
    origOf[r] = i;
    outCoordsF[4 * r + 0] = (float)b;
    outCoordsF[4 * r + 1] = (float)x;
    outCoordsF[4 * r + 2] = (float)y;
    outCoordsF[4 * r + 3] = (float)z;
    sortedCoordsI[4 * r + 0] = b;  // int copy for the conv kernel's int4 load
    sortedCoordsI[4 * r + 1] = x;
    sortedCoordsI[4 * r + 2] = y;
    sortedCoordsI[4 * r + 3] = z;
}

// 6) the conv: 8 points x 32 channel-lanes per block
__global__ __launch_bounds__(256) void k_conv(const float* __restrict__ feats, const float* __restrict__ weight,
                                              const int* __restrict__ sortedCoordsI,
                                              const unsigned* __restrict__ bitmask,
                                              const unsigned* __restrict__ wordPrefix,
                                              const int* __restrict__ origOf,
                                              float* __restrict__ out, int n) {
    __shared__ float sw[NPTS_C * NTAPS];
    for (int idx = threadIdx.x; idx < NPTS_C * NTAPS; idx += 256) sw[idx] = weight[idx];
    __syncthreads();

    int p = blockIdx.x * 8 + (threadIdx.x >> 5);
    int c = threadIdx.x & 31;
    if (p >= n) return;

    int4 co = ((const int4*)sortedCoordsI)[p]; // (b, x, y, z), same 16B row for all 32 lanes

    // lanes 0..26 each resolve one tap's neighbor (original feat index, -1 if absent)
    int nidx = -1;
    int k = c;
    if (k < NTAPS) {
        int dx = k / 9 - 1, dy = (k % 9) / 3 - 1, dz = k % 3 - 1;
        int x = co.y + dx, y = co.z + dy, z = co.w + dz;
        if ((unsigned)x < 256u && (unsigned)y < 256u && (unsigned)z < 256u) {
            unsigned key = make_key(co.x, x, y, z);
            unsigned word = key >> 5, bit = key & 31u;
            unsigned m = bitmask[word];
            if ((m >> bit) & 1u) {
                unsigned r = wordPrefix[word] + __popc(m & ((1u << bit) - 1u));
                nidx = origOf[r];
            }
        }
    }

    float acc = 0.0f;
    #pragma unroll
    for (int kk = 0; kk < NTAPS; kk++) {
        int g = __shfl(nidx, kk, 32);
        if (g >= 0) acc += feats[g * NPTS_C + c] * sw[c * NTAPS + kk];
    }
    out[p * NPTS_C + c] = acc;
}

extern "C" void kernel_launch(void* const* d_in, const int* in_sizes, int n_in,
                              void* d_out, int out_size, void* d_ws, size_t ws_size,
                              hipStream_t stream) {
    const float* feats  = (const float*)d_in[0];
    const int*   coords = (const int*)d_in[1];
    const float* weight = (const float*)d_in[2];
    const int n = in_sizes[1] / 4; // N points

    float* out        = (float*)d_out;              // [N, 32] f32
    float* outCoordsF = (float*)d_out + n * NPTS_C; // [N, 4] written as float values

    // workspace layout
    char* ws = (char*)d_ws;
    unsigned* bitmask      = (unsigned*)ws;                                  // 4 MB
    unsigned* wordPrefix   = (unsigned*)(ws + (size_t)KEY_WORDS * 4);        // 4 MB
    unsigned* blockSums    = (unsigned*)(ws + (size_t)KEY_WORDS * 8);        // 16 KB
    unsigned* blockOffsets = (unsigned*)(ws + (size_t)KEY_WORDS * 8 + SCAN_BLOCKS * 4); // 16 KB
    int*      origOf       = (int*)(ws + (size_t)KEY_WORDS * 8 + SCAN_BLOCKS * 8);      // N*4 B
    int*      sortedCoordsI= (int*)(ws + (size_t)KEY_WORDS * 8 + SCAN_BLOCKS * 8 + (size_t)n * 4); // N*16 B

    hipMemsetAsync(bitmask, 0, (size_t)KEY_WORDS * 4, stream);

    int tb = 256;
    k_scatter_bits<<<(n + tb - 1) / tb, tb, 0, stream>>>(coords, bitmask, n);
    k_popc_sums<<<SCAN_BLOCKS, 256, 0, stream>>>(bitmask, blockSums);
    k_scan_sums<<<1, 256, 0, stream>>>(blockSums, blockOffsets);
    k_word_prefix<<<SCAN_BLOCKS, 256, 0, stream>>>(bitmask, blockOffsets, wordPrefix);
    k_scatter_rank<<<(n + tb - 1) / tb, tb, 0, stream>>>(coords, bitmask, wordPrefix, origOf, outCoordsF, sortedCoordsI, n);
    k_conv<<<(n + 7) / 8, 256, 0, stream>>>(feats, weight, sortedCoordsI, bitmask, wordPrefix, origOf, out, n);
}

// Round 3
// 367.785 us; speedup vs baseline: 1.1308x; 1.1308x over previous
//
#include <hip/hip_runtime.h>

#define NPTS_C 32            // channels
#define NTAPS 27             // 3x3x3
#define KEY_WORDS (1u << 20) // 2^25 keys / 32 bits
#define SCAN_BLOCKS 1024     // KEY_WORDS / 1024 (each block handles 1024 words)

__device__ __forceinline__ unsigned make_key(int b, int x, int y, int z) {
    // ((b*256 + x)*256 + y)*256 + z ; b in {0,1}, x/y/z in [0,256)
    return ((((unsigned)b << 8 | (unsigned)x) << 8 | (unsigned)y) << 8) | (unsigned)z;
}

// 1) scatter occupancy bits
__global__ void k_scatter_bits(const int4* __restrict__ coords, unsigned* __restrict__ bitmask, int n) {
    int i = blockIdx.x * blockDim.x + threadIdx.x;
    if (i >= n) return;
    int4 co = coords[i];
    unsigned key = make_key(co.x, co.y, co.z, co.w);
    atomicOr(&bitmask[key >> 5], 1u << (key & 31u));
}

// 2) per-block (1024 words) popcount sums; thread t owns 4 consecutive words
__global__ void k_popc_sums(const uint4* __restrict__ bm4, unsigned* __restrict__ blockSums) {
    int t = threadIdx.x;
    uint4 w = bm4[blockIdx.x * 256 + t];
    unsigned s = __popc(w.x) + __popc(w.y) + __popc(w.z) + __popc(w.w);
    for (int off = 32; off > 0; off >>= 1) s += __shfl_down(s, off, 64);
    __shared__ unsigned wsum[4];
    if ((t & 63) == 0) wsum[t >> 6] = s;
    __syncthreads();
    if (t == 0) blockSums[blockIdx.x] = wsum[0] + wsum[1] + wsum[2] + wsum[3];
}

// 3) exclusive scan of 1024 block sums; single block, 256 threads x uint4
__global__ void k_scan_sums(const unsigned* __restrict__ blockSums, unsigned* __restrict__ blockOffsets) {
    int t = threadIdx.x, lane = t & 63;
    uint4 v = ((const uint4*)blockSums)[t];
    unsigned s = v.x + v.y + v.z + v.w;
    unsigned incl = s;
    for (int off = 1; off < 64; off <<= 1) {
        unsigned u = __shfl_up(incl, off, 64);
        if (lane >= off) incl += u;
    }
    __shared__ unsigned wsum[4];
    if (lane == 63) wsum[t >> 6] = incl;
    __syncthreads();
    unsigned waveBase = 0;
    int wv = t >> 6;
    for (int i = 0; i < wv; i++) waveBase += wsum[i];
    unsigned excl = waveBase + incl - s;
    uint4 o;
    o.x = excl; o.y = o.x + v.x; o.z = o.y + v.y; o.w = o.z + v.z;
    ((uint4*)blockOffsets)[t] = o;
}

// 4) build combined[word] = {bits, exclusive popcount prefix} (uint2), 8 MB
__global__ void k_build_combined(const uint4* __restrict__ bm4, const unsigned* __restrict__ blockOffsets,
                                 uint4* __restrict__ combined4) {
    int t = threadIdx.x, lane = t & 63;
    int gw = blockIdx.x * 256 + t; // uint4 index; words gw*4 .. gw*4+3
    uint4 w = bm4[gw];
    unsigned p0 = __popc(w.x), p1 = __popc(w.y), p2 = __popc(w.z), p3 = __popc(w.w);
    unsigned s = p0 + p1 + p2 + p3;
    unsigned incl = s;
    for (int off = 1; off < 64; off <<= 1) {
        unsigned u = __shfl_up(incl, off, 64);
        if (lane >= off) incl += u;
    }
    __shared__ unsigned wsum[4];
    if (lane == 63) wsum[t >> 6] = incl;
    __syncthreads();
    unsigned waveBase = 0;
    int wv = t >> 6;
    for (int i = 0; i < wv; i++) waveBase += wsum[i];
    unsigned excl = blockOffsets[blockIdx.x] + waveBase + incl - s;
    uint4 a; a.x = w.x; a.y = excl;           a.z = w.y; a.w = excl + p0;
    uint4 b; b.x = w.z; b.y = excl + p0 + p1; b.z = w.w; b.w = excl + p0 + p1 + p2;
    combined4[gw * 2 + 0] = a; // contiguous 32B per thread -> coalesced
    combined4[gw * 2 + 1] = b;
}

// 5) rank each input point, scatter only origOf[rank] = i (4B)
__global__ void k_scatter_rank(const int4* __restrict__ coords, const uint2* __restrict__ combined,
                               int* __restrict__ origOf, int n) {
    int i = blockIdx.x * blockDim.x + threadIdx.x;
    if (i >= n) return;
    int4 co = coords[i];
    unsigned key = make_key(co.x, co.y, co.z, co.w);
    uint2 cw = combined[key >> 5];
    unsigned bit = key & 31u;
    unsigned r = cw.y + __popc(cw.x & ((1u << bit) - 1u));
    origOf[r] = i;
}

// 6) conv: 8 points x 32 channel-lanes per block.
//    Lanes 0..8 probe one word per (dx,dy) (3 dz taps share a word except at
//    z%32 boundaries); lanes 0..26 resolve their tap; ballot-compacted
//    accumulation loop (~1.5 iterations avg instead of 27).
__global__ __launch_bounds__(256) void k_conv(const float* __restrict__ feats, const float* __restrict__ weight,
                                              const int4* __restrict__ coords,
                                              const uint2* __restrict__ combined,
                                              const int* __restrict__ origOf,
                                              float* __restrict__ out, float* __restrict__ outCoordsF, int n) {
    __shared__ float swT[NTAPS * 32]; // transposed: swT[k*32+c] = weight[c*27+k]
    for (int idx = threadIdx.x; idx < NTAPS * 32; idx += 256) {
        int kk = idx >> 5, cc = idx & 31;
        swT[idx] = weight[cc * NTAPS + kk];
    }
    __syncthreads();

    int p = blockIdx.x * 8 + (threadIdx.x >> 5);
    int c = threadIdx.x & 31;
    if (p >= n) return;

    int orig = origOf[p];          // sorted position p -> original row
    int4 co = coords[orig];        // broadcast (all 32 lanes same address)

    if (c == 0) {
        float4 f; f.x = (float)co.x; f.y = (float)co.y; f.z = (float)co.z; f.w = (float)co.w;
        ((float4*)outCoordsF)[p] = f; // sorted coords as float VALUES (harness reads f32)
    }

    int k = c; // tap id for lanes 0..26
    int dx = k / 9 - 1, dy = (k % 9) / 3 - 1, dz = k % 3 - 1;
    int x = co.y + dx, y = co.z + dy, z = co.w + dz;
    bool valid = (k < NTAPS) && ((unsigned)x < 256u) && ((unsigned)y < 256u) && ((unsigned)z < 256u);

    // probing lanes 0..8: word containing (dxj, dyj, center z)
    uint2 cw; cw.x = 0u; cw.y = 0u;
    if (k < 9) {
        int dxj = k / 3 - 1, dyj = k % 3 - 1;
        int xj = co.y + dxj, yj = co.z + dyj;
        if ((unsigned)xj < 256u && (unsigned)yj < 256u) {
            unsigned keyj = make_key(co.x, xj, yj, co.w);
            cw = combined[keyj >> 5];
        }
    }
    int j = k / 3; // tap k's probing lane (same dx,dy)
    unsigned bb = __shfl(cw.x, j, 32);
    unsigned pp = __shfl(cw.y, j, 32);

    int nidx = -1;
    if (valid) {
        unsigned keyk = make_key(co.x, x, y, z);
        if ((z >> 5) != (co.w >> 5)) { // z crossed a 32-word boundary: self-probe
            uint2 t2 = combined[keyk >> 5];
            bb = t2.x; pp = t2.y;
        }
        unsigned bit = keyk & 31u;
        if ((bb >> bit) & 1u)
            nidx = origOf[pp + __popc(bb & ((1u << bit) - 1u))];
    }

    unsigned long long full = __ballot(nidx >= 0);
    unsigned mymask = (threadIdx.x & 32) ? (unsigned)(full >> 32) : (unsigned)full;

    float acc = 0.0f;
    while (mymask) {
        int kk = __ffs(mymask) - 1;
        mymask &= mymask - 1;
        int g = __shfl(nidx, kk, 32);
        acc += feats[g * NPTS_C + c] * swT[kk * 32 + c];
    }
    out[p * NPTS_C + c] = acc;
}

extern "C" void kernel_launch(void* const* d_in, const int* in_sizes, int n_in,
                              void* d_out, int out_size, void* d_ws, size_t ws_size,
                              hipStream_t stream) {
    const float* feats  = (const float*)d_in[0];
    const int4*  coords = (const int4*)d_in[1];
    const float* weight = (const float*)d_in[2];
    const int n = in_sizes[1] / 4;

    float* out        = (float*)d_out;              // [N, 32] f32
    float* outCoordsF = (float*)d_out + n * NPTS_C; // [N, 4] float values

    // workspace layout (16B-aligned segments)
    char* ws = (char*)d_ws;
    unsigned* bitmask      = (unsigned*)ws;                                   // 4 MB
    uint2*    combined     = (uint2*)(ws + (size_t)KEY_WORDS * 4);            // 8 MB
    unsigned* blockSums    = (unsigned*)(ws + (size_t)KEY_WORDS * 12);        // 4 KB
    unsigned* blockOffsets = (unsigned*)(ws + (size_t)KEY_WORDS * 12 + 4096); // 4 KB
    int*      origOf       = (int*)(ws + (size_t)KEY_WORDS * 12 + 8192);      // N*4 B

    hipMemsetAsync(bitmask, 0, (size_t)KEY_WORDS * 4, stream);

    int tb = 256;
    k_scatter_bits<<<(n + tb - 1) / tb, tb, 0, stream>>>(coords, bitmask, n);
    k_popc_sums<<<SCAN_BLOCKS, 256, 0, stream>>>((const uint4*)bitmask, blockSums);
    k_scan_sums<<<1, 256, 0, stream>>>(blockSums, blockOffsets);
    k_build_combined<<<SCAN_BLOCKS, 256, 0, stream>>>((const uint4*)bitmask, blockOffsets, (uint4*)combined);
    k_scatter_rank<<<(n + tb - 1) / tb, tb, 0, stream>>>(coords, combined, origOf, n);
    k_conv<<<(n + 7) / 8, 256, 0, stream>>>(feats, weight, coords, combined, origOf, out, outCoordsF, n);
}

// Round 4
// 360.935 us; speedup vs baseline: 1.1522x; 1.0190x over previous
//
#include <hip/hip_runtime.h>

#define NPTS_C 32            // channels
#define NTAPS 27             // 3x3x3
#define KEY_WORDS (1u << 20) // 2^25 keys / 32 bits
#define SCAN_BLOCKS 1024     // KEY_WORDS / 1024 (each block handles 1024 words)

__device__ __forceinline__ unsigned make_key(int b, int x, int y, int z) {
    // ((b*256 + x)*256 + y)*256 + z ; b in {0,1}, x/y/z in [0,256)
    return ((((unsigned)b << 8 | (unsigned)x) << 8 | (unsigned)y) << 8) | (unsigned)z;
}

// 1) scatter occupancy bits
__global__ void k_scatter_bits(const int4* __restrict__ coords, unsigned* __restrict__ bitmask, int n) {
    int i = blockIdx.x * blockDim.x + threadIdx.x;
    if (i >= n) return;
    int4 co = coords[i];
    unsigned key = make_key(co.x, co.y, co.z, co.w);
    atomicOr(&bitmask[key >> 5], 1u << (key & 31u));
}

// 2) per-block (1024 words) popcount sums; thread t owns 4 consecutive words
__global__ void k_popc_sums(const uint4* __restrict__ bm4, unsigned* __restrict__ blockSums) {
    int t = threadIdx.x;
    uint4 w = bm4[blockIdx.x * 256 + t];
    unsigned s = __popc(w.x) + __popc(w.y) + __popc(w.z) + __popc(w.w);
    for (int off = 32; off > 0; off >>= 1) s += __shfl_down(s, off, 64);
    __shared__ unsigned wsum[4];
    if ((t & 63) == 0) wsum[t >> 6] = s;
    __syncthreads();
    if (t == 0) blockSums[blockIdx.x] = wsum[0] + wsum[1] + wsum[2] + wsum[3];
}

// 3) build combined[word] = {bits, exclusive popcount prefix} (uint2), 8 MB.
//    Each block computes its own offset by summing blockSums[0..blockIdx) (L2-hot).
__global__ void k_build_combined(const uint4* __restrict__ bm4, const unsigned* __restrict__ blockSums,
                                 uint4* __restrict__ combined4) {
    int t = threadIdx.x, lane = t & 63;
    __shared__ unsigned preW[4];
    __shared__ unsigned wsum[4];

    // exclusive block offset
    unsigned pre = 0;
    for (int i = t; i < blockIdx.x; i += 256) pre += blockSums[i];
    for (int off = 32; off > 0; off >>= 1) pre += __shfl_down(pre, off, 64);
    if (lane == 0) preW[t >> 6] = pre;
    __syncthreads();
    unsigned blockBase = preW[0] + preW[1] + preW[2] + preW[3];

    int gw = blockIdx.x * 256 + t; // uint4 index; words gw*4 .. gw*4+3
    uint4 w = bm4[gw];
    unsigned p0 = __popc(w.x), p1 = __popc(w.y), p2 = __popc(w.z), p3 = __popc(w.w);
    unsigned s = p0 + p1 + p2 + p3;
    unsigned incl = s;
    for (int off = 1; off < 64; off <<= 1) {
        unsigned u = __shfl_up(incl, off, 64);
        if (lane >= off) incl += u;
    }
    if (lane == 63) wsum[t >> 6] = incl;
    __syncthreads();
    unsigned waveBase = 0;
    int wv = t >> 6;
    for (int i = 0; i < wv; i++) waveBase += wsum[i];
    unsigned excl = blockBase + waveBase + incl - s;
    uint4 a; a.x = w.x; a.y = excl;           a.z = w.y; a.w = excl + p0;
    uint4 b; b.x = w.z; b.y = excl + p0 + p1; b.z = w.w; b.w = excl + p0 + p1 + p2;
    combined4[gw * 2 + 0] = a;
    combined4[gw * 2 + 1] = b;
}

__device__ __forceinline__ unsigned rank_of(unsigned key, const uint2* __restrict__ combined) {
    uint2 cw = combined[key >> 5];
    unsigned bit = key & 31u;
    return cw.y + __popc(cw.x & ((1u << bit) - 1u));
}

// ---------------- BIG-WS PATH ----------------
// 4a) fused rank + permute: sfeats[r] = feats[i]; coords(float) -> d_out.
//     8 points per 256-block, 32 channel-lanes per point.
__global__ __launch_bounds__(256) void k_scatter_gather(const float* __restrict__ feats,
                                                        const int4* __restrict__ coords,
                                                        const uint2* __restrict__ combined,
                                                        float* __restrict__ sfeats,
                                                        float* __restrict__ outCoordsF, int n) {
    int i = blockIdx.x * 8 + (threadIdx.x >> 5);
    int c = threadIdx.x & 31;
    if (i >= n) return;
    int4 co = coords[i];                                  // broadcast within half-wave
    float f = feats[i * NPTS_C + c];                      // coalesced read (independent of rank)
    unsigned key = make_key(co.x, co.y, co.z, co.w);
    unsigned r = rank_of(key, combined);
    sfeats[r * NPTS_C + c] = f;                           // 128 B contiguous per point
    if (c == 0) {
        float4 fc; fc.x = (float)co.x; fc.y = (float)co.y; fc.z = (float)co.z; fc.w = (float)co.w;
        ((float4*)outCoordsF)[r] = fc;                    // harness reads coords as f32 values
    }
}

// 5a) conv on permuted feats: tap -> rank -> sfeats[rank]. No origOf hop.
__global__ __launch_bounds__(256) void k_conv_sorted(const float* __restrict__ sfeats,
                                                     const float* __restrict__ weight,
                                                     const float* __restrict__ outCoordsF,
                                                     const uint2* __restrict__ combined,
                                                     float* __restrict__ out, int n) {
    __shared__ float swT[NTAPS * 32]; // swT[k*32+c] = weight[c*27+k]
    for (int idx = threadIdx.x; idx < NTAPS * 32; idx += 256) {
        int kk = idx >> 5, cc = idx & 31;
        swT[idx] = weight[cc * NTAPS + kk];
    }
    __syncthreads();

    int p = blockIdx.x * 8 + (threadIdx.x >> 5);
    int c = threadIdx.x & 31;
    if (p >= n) return;

    float4 cf = ((const float4*)outCoordsF)[p];           // coalesced-ish (8 pts/block)
    int cb = (int)cf.x, cx = (int)cf.y, cy = (int)cf.z, cz = (int)cf.w;

    int k = c;
    int dx = k / 9 - 1, dy = (k % 9) / 3 - 1, dz = k % 3 - 1;
    int x = cx + dx, y = cy + dy, z = cz + dz;
    bool valid = (k < NTAPS) && ((unsigned)x < 256u) && ((unsigned)y < 256u) && ((unsigned)z < 256u);

    // lanes 0..8 probe the word for (dx,dy, center z); 3 dz taps usually share it
    uint2 cw; cw.x = 0u; cw.y = 0u;
    if (k < 9) {
        int dxj = k / 3 - 1, dyj = k % 3 - 1;
        int xj = cx + dxj, yj = cy + dyj;
        if ((unsigned)xj < 256u && (unsigned)yj < 256u)
            cw = combined[make_key(cb, xj, yj, cz) >> 5];
    }
    int j = k / 3;
    unsigned bb = __shfl(cw.x, j, 32);
    unsigned pp = __shfl(cw.y, j, 32);

    int nidx = -1; // = sorted rank of the neighbor
    if (valid) {
        unsigned keyk = make_key(cb, x, y, z);
        if ((z >> 5) != (cz >> 5)) { // z crossed 32-word boundary: self-probe
            uint2 t2 = combined[keyk >> 5];
            bb = t2.x; pp = t2.y;
        }
        unsigned bit = keyk & 31u;
        if ((bb >> bit) & 1u)
            nidx = (int)(pp + __popc(bb & ((1u << bit) - 1u)));
    }

    unsigned long long full = __ballot(nidx >= 0);
    unsigned mymask = (threadIdx.x & 32) ? (unsigned)(full >> 32) : (unsigned)full;

    float acc = 0.0f;
    while (mymask) {
        int kk = __ffs(mymask) - 1;
        mymask &= mymask - 1;
        int g = __shfl(nidx, kk, 32);
        acc += sfeats[g * NPTS_C + c] * swT[kk * 32 + c];
    }
    out[p * NPTS_C + c] = acc;
}

// ---------------- FALLBACK (small ws) — R3 path ----------------
__global__ void k_scatter_rank(const int4* __restrict__ coords, const uint2* __restrict__ combined,
                               int* __restrict__ origOf, int n) {
    int i = blockIdx.x * blockDim.x + threadIdx.x;
    if (i >= n) return;
    int4 co = coords[i];
    unsigned r = rank_of(make_key(co.x, co.y, co.z, co.w), combined);
    origOf[r] = i;
}

__global__ __launch_bounds__(256) void k_conv_indirect(const float* __restrict__ feats, const float* __restrict__ weight,
                                                       const int4* __restrict__ coords,
                                                       const uint2* __restrict__ combined,
                                                       const int* __restrict__ origOf,
                                                       float* __restrict__ out, float* __restrict__ outCoordsF, int n) {
    __shared__ float swT[NTAPS * 32];
    for (int idx = threadIdx.x; idx < NTAPS * 32; idx += 256) {
        int kk = idx >> 5, cc = idx & 31;
        swT[idx] = weight[cc * NTAPS + kk];
    }
    __syncthreads();

    int p = blockIdx.x * 8 + (threadIdx.x >> 5);
    int c = threadIdx.x & 31;
    if (p >= n) return;

    int orig = origOf[p];
    int4 co = coords[orig];
    if (c == 0) {
        float4 f; f.x = (float)co.x; f.y = (float)co.y; f.z = (float)co.z; f.w = (float)co.w;
        ((float4*)outCoordsF)[p] = f;
    }

    int k = c;
    int dx = k / 9 - 1, dy = (k % 9) / 3 - 1, dz = k % 3 - 1;
    int x = co.y + dx, y = co.z + dy, z = co.w + dz;
    bool valid = (k < NTAPS) && ((unsigned)x < 256u) && ((unsigned)y < 256u) && ((unsigned)z < 256u);

    uint2 cw; cw.x = 0u; cw.y = 0u;
    if (k < 9) {
        int dxj = k / 3 - 1, dyj = k % 3 - 1;
        int xj = co.y + dxj, yj = co.z + dyj;
        if ((unsigned)xj < 256u && (unsigned)yj < 256u)
            cw = combined[make_key(co.x, xj, yj, co.w) >> 5];
    }
    int j = k / 3;
    unsigned bb = __shfl(cw.x, j, 32);
    unsigned pp = __shfl(cw.y, j, 32);

    int nidx = -1;
    if (valid) {
        unsigned keyk = make_key(co.x, x, y, z);
        if ((z >> 5) != (co.w >> 5)) {
            uint2 t2 = combined[keyk >> 5];
            bb = t2.x; pp = t2.y;
        }
        unsigned bit = keyk & 31u;
        if ((bb >> bit) & 1u)
            nidx = origOf[pp + __popc(bb & ((1u << bit) - 1u))];
    }

    unsigned long long full = __ballot(nidx >= 0);
    unsigned mymask = (threadIdx.x & 32) ? (unsigned)(full >> 32) : (unsigned)full;

    float acc = 0.0f;
    while (mymask) {
        int kk = __ffs(mymask) - 1;
        mymask &= mymask - 1;
        int g = __shfl(nidx, kk, 32);
        acc += feats[g * NPTS_C + c] * swT[kk * 32 + c];
    }
    out[p * NPTS_C + c] = acc;
}

extern "C" void kernel_launch(void* const* d_in, const int* in_sizes, int n_in,
                              void* d_out, int out_size, void* d_ws, size_t ws_size,
                              hipStream_t stream) {
    const float* feats  = (const float*)d_in[0];
    const int4*  coords = (const int4*)d_in[1];
    const float* weight = (const float*)d_in[2];
    const int n = in_sizes[1] / 4;

    float* out        = (float*)d_out;              // [N, 32] f32
    float* outCoordsF = (float*)d_out + n * NPTS_C; // [N, 4] float values

    char* ws = (char*)d_ws;
    unsigned* bitmask   = (unsigned*)ws;                               // 4 MB
    uint2*    combined  = (uint2*)(ws + (size_t)KEY_WORDS * 4);        // 8 MB
    unsigned* blockSums = (unsigned*)(ws + (size_t)KEY_WORDS * 12);    // 4 KB
    char*     rest      = ws + (size_t)KEY_WORDS * 12 + 4096;

    size_t need_big = (size_t)KEY_WORDS * 12 + 4096 + (size_t)n * NPTS_C * 4;
    bool big = ws_size >= need_big;

    hipMemsetAsync(bitmask, 0, (size_t)KEY_WORDS * 4, stream);

    int tb = 256;
    k_scatter_bits<<<(n + tb - 1) / tb, tb, 0, stream>>>(coords, bitmask, n);
    k_popc_sums<<<SCAN_BLOCKS, 256, 0, stream>>>((const uint4*)bitmask, blockSums);
    k_build_combined<<<SCAN_BLOCKS, 256, 0, stream>>>((const uint4*)bitmask, blockSums, (uint4*)combined);

    if (big) {
        float* sfeats = (float*)rest; // N*32 f32 = 76.8 MB
        k_scatter_gather<<<(n + 7) / 8, 256, 0, stream>>>(feats, coords, combined, sfeats, outCoordsF, n);
        k_conv_sorted<<<(n + 7) / 8, 256, 0, stream>>>(sfeats, weight, outCoordsF, combined, out, n);
    } else {
        int* origOf = (int*)rest;     // N*4 B
        k_scatter_rank<<<(n + tb - 1) / tb, tb, 0, stream>>>(coords, combined, origOf, n);
        k_conv_indirect<<<(n + 7) / 8, 256, 0, stream>>>(feats, weight, coords, combined, origOf, out, outCoordsF, n);
    }
}

// Round 5
// 322.275 us; speedup vs baseline: 1.2904x; 1.1200x over previous
//
#include <hip/hip_runtime.h>

#define NPTS_C 32            // channels
#define NTAPS 27             // 3x3x3
#define KEY_WORDS (1u << 20) // 2^25 keys / 32 bits
#define SCAN_BLOCKS 1024     // KEY_WORDS / 1024 words per block

__device__ __forceinline__ unsigned make_key(int b, int x, int y, int z) {
    return ((((unsigned)b << 8 | (unsigned)x) << 8 | (unsigned)y) << 8) | (unsigned)z;
}

// 1) scatter occupancy bits
__global__ void k_scatter_bits(const int4* __restrict__ coords, unsigned* __restrict__ bitmask, int n) {
    int i = blockIdx.x * blockDim.x + threadIdx.x;
    if (i >= n) return;
    int4 co = coords[i];
    unsigned key = make_key(co.x, co.y, co.z, co.w);
    atomicOr(&bitmask[key >> 5], 1u << (key & 31u));
}

// 2) per-block (1024 words) popcount sums
__global__ void k_popc_sums(const uint4* __restrict__ bm4, unsigned* __restrict__ blockSums) {
    int t = threadIdx.x;
    uint4 w = bm4[blockIdx.x * 256 + t];
    unsigned s = __popc(w.x) + __popc(w.y) + __popc(w.z) + __popc(w.w);
    for (int off = 32; off > 0; off >>= 1) s += __shfl_down(s, off, 64);
    __shared__ unsigned wsum[4];
    if ((t & 63) == 0) wsum[t >> 6] = s;
    __syncthreads();
    if (t == 0) blockSums[blockIdx.x] = wsum[0] + wsum[1] + wsum[2] + wsum[3];
}

// 3) combined[word] = {bits, exclusive prefix popcount}; block offset from L2-hot blockSums
__global__ void k_build_combined(const uint4* __restrict__ bm4, const unsigned* __restrict__ blockSums,
                                 uint4* __restrict__ combined4) {
    int t = threadIdx.x, lane = t & 63;
    __shared__ unsigned preW[4];
    __shared__ unsigned wsum[4];

    unsigned pre = 0;
    for (int i = t; i < blockIdx.x; i += 256) pre += blockSums[i];
    for (int off = 32; off > 0; off >>= 1) pre += __shfl_down(pre, off, 64);
    if (lane == 0) preW[t >> 6] = pre;
    __syncthreads();
    unsigned blockBase = preW[0] + preW[1] + preW[2] + preW[3];

    int gw = blockIdx.x * 256 + t;
    uint4 w = bm4[gw];
    unsigned p0 = __popc(w.x), p1 = __popc(w.y), p2 = __popc(w.z), p3 = __popc(w.w);
    unsigned s = p0 + p1 + p2 + p3;
    unsigned incl = s;
    for (int off = 1; off < 64; off <<= 1) {
        unsigned u = __shfl_up(incl, off, 64);
        if (lane >= off) incl += u;
    }
    if (lane == 63) wsum[t >> 6] = incl;
    __syncthreads();
    unsigned waveBase = 0;
    int wv = t >> 6;
    for (int i = 0; i < wv; i++) waveBase += wsum[i];
    unsigned excl = blockBase + waveBase + incl - s;
    uint4 a; a.x = w.x; a.y = excl;           a.z = w.y; a.w = excl + p0;
    uint4 b; b.x = w.z; b.y = excl + p0 + p1; b.z = w.w; b.w = excl + p0 + p1 + p2;
    combined4[gw * 2 + 0] = a;
    combined4[gw * 2 + 1] = b;
}

__device__ __forceinline__ unsigned rank_of(unsigned key, const uint2* __restrict__ combined) {
    uint2 cw = combined[key >> 5];
    unsigned bit = key & 31u;
    return cw.y + __popc(cw.x & ((1u << bit) - 1u));
}

// 4) origOf[rank] = original index (4 B scatter — cheap)
__global__ void k_scatter_rank(const int4* __restrict__ coords, const uint2* __restrict__ combined,
                               int* __restrict__ origOf, int n) {
    int i = blockIdx.x * blockDim.x + threadIdx.x;
    if (i >= n) return;
    int4 co = coords[i];
    unsigned r = rank_of(make_key(co.x, co.y, co.z, co.w), combined);
    origOf[r] = i;
}

// 5) rank-order gather: scattered 128B READS, coalesced writes. 2 points per 32-group.
__global__ __launch_bounds__(256) void k_gather_sorted(const float* __restrict__ feats,
                                                       const int4* __restrict__ coords,
                                                       const int* __restrict__ origOf,
                                                       float* __restrict__ sfeats,
                                                       float* __restrict__ outCoordsF, int n) {
    int gi = threadIdx.x >> 5, c = threadIdx.x & 31;
    int pA = blockIdx.x * 16 + gi * 2, pB = pA + 1;
    bool hasA = pA < n, hasB = pB < n;
    int pAc = hasA ? pA : 0, pBc = hasB ? pB : 0;

    int oA = origOf[pAc];                  // broadcast within group
    int oB = origOf[pBc];
    float fA = feats[(size_t)oA * NPTS_C + c]; // two independent 128B gathers (MLP)
    float fB = feats[(size_t)oB * NPTS_C + c];
    int4 cA = coords[oA];
    int4 cB = coords[oB];

    if (hasA) sfeats[(size_t)pA * NPTS_C + c] = fA;
    if (hasB) sfeats[(size_t)pB * NPTS_C + c] = fB;
    if (c == 0) {
        if (hasA) { float4 f; f.x=(float)cA.x; f.y=(float)cA.y; f.z=(float)cA.z; f.w=(float)cA.w; ((float4*)outCoordsF)[pA]=f; }
        if (hasB) { float4 f; f.x=(float)cB.x; f.y=(float)cB.y; f.z=(float)cB.z; f.w=(float)cB.w; ((float4*)outCoordsF)[pB]=f; }
    }
}

// tap resolution for lane k of a 32-group; returns neighbor's sorted rank or -1
__device__ __forceinline__ int resolve_tap(int cb, int cx, int cy, int cz, int k,
                                           const uint2* __restrict__ combined) {
    int dx = k / 9 - 1, dy = (k % 9) / 3 - 1, dz = k % 3 - 1;
    int x = cx + dx, y = cy + dy, z = cz + dz;
    bool valid = (k < NTAPS) && ((unsigned)x < 256u) && ((unsigned)y < 256u) && ((unsigned)z < 256u);

    uint2 cw; cw.x = 0u; cw.y = 0u;
    if (k < 9) { // lanes 0..8 probe the word for (dx,dy, center z)
        int dxj = k / 3 - 1, dyj = k % 3 - 1;
        int xj = cx + dxj, yj = cy + dyj;
        if ((unsigned)xj < 256u && (unsigned)yj < 256u)
            cw = combined[make_key(cb, xj, yj, cz) >> 5];
    }
    int j = k / 3;
    unsigned bb = __shfl(cw.x, j, 32);
    unsigned pp = __shfl(cw.y, j, 32);

    int nidx = -1;
    if (valid) {
        unsigned keyk = make_key(cb, x, y, z);
        if ((z >> 5) != (cz >> 5)) { // crossed 32-bit word boundary in z: self-probe
            uint2 t2 = combined[keyk >> 5];
            bb = t2.x; pp = t2.y;
        }
        unsigned bit = keyk & 31u;
        if ((bb >> bit) & 1u)
            nidx = (int)(pp + __popc(bb & ((1u << bit) - 1u)));
    }
    return nidx;
}

// 6) conv on permuted feats: 2 points per 32-group (16 per block), merged accumulate loop
__global__ __launch_bounds__(256) void k_conv_sorted(const float* __restrict__ sfeats,
                                                     const float* __restrict__ weight,
                                                     const float* __restrict__ outCoordsF,
                                                     const uint2* __restrict__ combined,
                                                     float* __restrict__ out, int n) {
    __shared__ float swT[NTAPS * 32]; // swT[k*32+c] = weight[c*27+k]
    for (int idx = threadIdx.x; idx < NTAPS * 32; idx += 256) {
        int kk = idx >> 5, cc = idx & 31;
        swT[idx] = weight[cc * NTAPS + kk];
    }
    __syncthreads();

    int gi = threadIdx.x >> 5, c = threadIdx.x & 31;
    int pA = blockIdx.x * 16 + gi * 2, pB = pA + 1;
    bool hasA = pA < n, hasB = pB < n;
    int pAc = hasA ? pA : 0, pBc = hasB ? pB : 0;

    float4 cfA = ((const float4*)outCoordsF)[pAc];
    float4 cfB = ((const float4*)outCoordsF)[pBc];
    int bA = (int)cfA.x, xA = (int)cfA.y, yA = (int)cfA.z, zA = (int)cfA.w;
    int bB = (int)cfB.x, xB = (int)cfB.y, yB = (int)cfB.z, zB = (int)cfB.w;

    int nidxA = resolve_tap(bA, xA, yA, zA, c, combined);
    int nidxB = resolve_tap(bB, xB, yB, zB, c, combined);

    unsigned long long balA = __ballot(nidxA >= 0);
    unsigned long long balB = __ballot(nidxB >= 0);
    bool hi = (threadIdx.x & 32) != 0;
    unsigned maskA = hi ? (unsigned)(balA >> 32) : (unsigned)balA;
    unsigned maskB = hi ? (unsigned)(balB >> 32) : (unsigned)balB;

    float accA = 0.0f, accB = 0.0f;
    while (maskA | maskB) { // masks are uniform within each 32-group
        if (maskA) {
            int kk = __ffs(maskA) - 1; maskA &= maskA - 1;
            int g = __shfl(nidxA, kk, 32);
            accA += sfeats[(size_t)g * NPTS_C + c] * swT[kk * 32 + c];
        }
        if (maskB) {
            int kk = __ffs(maskB) - 1; maskB &= maskB - 1;
            int g = __shfl(nidxB, kk, 32);
            accB += sfeats[(size_t)g * NPTS_C + c] * swT[kk * 32 + c];
        }
    }
    if (hasA) __builtin_nontemporal_store(accA, &out[(size_t)pA * NPTS_C + c]);
    if (hasB) __builtin_nontemporal_store(accB, &out[(size_t)pB * NPTS_C + c]);
}

// ---------------- FALLBACK (small ws) — R3 path ----------------
__global__ __launch_bounds__(256) void k_conv_indirect(const float* __restrict__ feats, const float* __restrict__ weight,
                                                       const int4* __restrict__ coords,
                                                       const uint2* __restrict__ combined,
                                                       const int* __restrict__ origOf,
                                                       float* __restrict__ out, float* __restrict__ outCoordsF, int n) {
    __shared__ float swT[NTAPS * 32];
    for (int idx = threadIdx.x; idx < NTAPS * 32; idx += 256) {
        int kk = idx >> 5, cc = idx & 31;
        swT[idx] = weight[cc * NTAPS + kk];
    }
    __syncthreads();

    int p = blockIdx.x * 8 + (threadIdx.x >> 5);
    int c = threadIdx.x & 31;
    if (p >= n) return;

    int orig = origOf[p];
    int4 co = coords[orig];
    if (c == 0) {
        float4 f; f.x = (float)co.x; f.y = (float)co.y; f.z = (float)co.z; f.w = (float)co.w;
        ((float4*)outCoordsF)[p] = f;
    }

    int nidx0 = resolve_tap(co.x, co.y, co.z, co.w, c, combined);
    int nidx = (nidx0 >= 0) ? origOf[nidx0] : -1;

    unsigned long long full = __ballot(nidx >= 0);
    unsigned mymask = (threadIdx.x & 32) ? (unsigned)(full >> 32) : (unsigned)full;

    float acc = 0.0f;
    while (mymask) {
        int kk = __ffs(mymask) - 1;
        mymask &= mymask - 1;
        int g = __shfl(nidx, kk, 32);
        acc += feats[(size_t)g * NPTS_C + c] * swT[kk * 32 + c];
    }
    out[(size_t)p * NPTS_C + c] = acc;
}

extern "C" void kernel_launch(void* const* d_in, const int* in_sizes, int n_in,
                              void* d_out, int out_size, void* d_ws, size_t ws_size,
                              hipStream_t stream) {
    const float* feats  = (const float*)d_in[0];
    const int4*  coords = (const int4*)d_in[1];
    const float* weight = (const float*)d_in[2];
    const int n = in_sizes[1] / 4;

    float* out        = (float*)d_out;              // [N, 32] f32
    float* outCoordsF = (float*)d_out + n * NPTS_C; // [N, 4] float values

    char* ws = (char*)d_ws;
    unsigned* bitmask   = (unsigned*)ws;                               // 4 MB (reused as origOf after build)
    uint2*    combined  = (uint2*)(ws + (size_t)KEY_WORDS * 4);        // 8 MB
    unsigned* blockSums = (unsigned*)(ws + (size_t)KEY_WORDS * 12);    // 4 KB
    char*     rest      = ws + (size_t)KEY_WORDS * 12 + 4096;

    int* origOf = (int*)bitmask; // bitmask is dead after k_build_combined; N*4 <= 4 MB

    size_t need_big = (size_t)KEY_WORDS * 12 + 4096 + (size_t)n * NPTS_C * 4;
    bool big = ws_size >= need_big;

    hipMemsetAsync(bitmask, 0, (size_t)KEY_WORDS * 4, stream);

    int tb = 256;
    k_scatter_bits<<<(n + tb - 1) / tb, tb, 0, stream>>>(coords, bitmask, n);
    k_popc_sums<<<SCAN_BLOCKS, 256, 0, stream>>>((const uint4*)bitmask, blockSums);
    k_build_combined<<<SCAN_BLOCKS, 256, 0, stream>>>((const uint4*)bitmask, blockSums, (uint4*)combined);
    k_scatter_rank<<<(n + tb - 1) / tb, tb, 0, stream>>>(coords, combined, origOf, n);

    if (big) {
        float* sfeats = (float*)rest; // N*32 f32 = 76.8 MB
        k_gather_sorted<<<(n + 15) / 16, 256, 0, stream>>>(feats, coords, origOf, sfeats, outCoordsF, n);
        k_conv_sorted<<<(n + 15) / 16, 256, 0, stream>>>(sfeats, weight, outCoordsF, combined, out, n);
    } else {
        k_conv_indirect<<<(n + 7) / 8, 256, 0, stream>>>(feats, weight, coords, combined, origOf, out, outCoordsF, n);
    }
}

// Round 7
// 263.872 us; speedup vs baseline: 1.5760x; 1.2213x over previous
//
#include <hip/hip_runtime.h>

#define NPTS_C 32            // channels
#define NTAPS 27             // 3x3x3
#define KEY_WORDS (1u << 20) // 2^25 keys / 32 bits
#define SCAN_BLOCKS 1024     // KEY_WORDS / 1024 words per block

typedef float f32x4 __attribute__((ext_vector_type(4))); // native vec for nontemporal store

__device__ __forceinline__ unsigned make_key(int b, int x, int y, int z) {
    return ((((unsigned)b << 8 | (unsigned)x) << 8 | (unsigned)y) << 8) | (unsigned)z;
}

// 1) scatter occupancy bits
__global__ void k_scatter_bits(const int4* __restrict__ coords, unsigned* __restrict__ bitmask, int n) {
    int i = blockIdx.x * blockDim.x + threadIdx.x;
    if (i >= n) return;
    int4 co = coords[i];
    unsigned key = make_key(co.x, co.y, co.z, co.w);
    atomicOr(&bitmask[key >> 5], 1u << (key & 31u));
}

// 2) per-block (1024 words) popcount sums
__global__ void k_popc_sums(const uint4* __restrict__ bm4, unsigned* __restrict__ blockSums) {
    int t = threadIdx.x;
    uint4 w = bm4[blockIdx.x * 256 + t];
    unsigned s = __popc(w.x) + __popc(w.y) + __popc(w.z) + __popc(w.w);
    for (int off = 32; off > 0; off >>= 1) s += __shfl_down(s, off, 64);
    __shared__ unsigned wsum[4];
    if ((t & 63) == 0) wsum[t >> 6] = s;
    __syncthreads();
    if (t == 0) blockSums[blockIdx.x] = wsum[0] + wsum[1] + wsum[2] + wsum[3];
}

// 3) combined[word] = {bits, exclusive prefix popcount}
__global__ void k_build_combined(const uint4* __restrict__ bm4, const unsigned* __restrict__ blockSums,
                                 uint4* __restrict__ combined4) {
    int t = threadIdx.x, lane = t & 63;
    __shared__ unsigned preW[4];
    __shared__ unsigned wsum[4];

    unsigned pre = 0;
    for (int i = t; i < blockIdx.x; i += 256) pre += blockSums[i];
    for (int off = 32; off > 0; off >>= 1) pre += __shfl_down(pre, off, 64);
    if (lane == 0) preW[t >> 6] = pre;
    __syncthreads();
    unsigned blockBase = preW[0] + preW[1] + preW[2] + preW[3];

    int gw = blockIdx.x * 256 + t;
    uint4 w = bm4[gw];
    unsigned p0 = __popc(w.x), p1 = __popc(w.y), p2 = __popc(w.z), p3 = __popc(w.w);
    unsigned s = p0 + p1 + p2 + p3;
    unsigned incl = s;
    for (int off = 1; off < 64; off <<= 1) {
        unsigned u = __shfl_up(incl, off, 64);
        if (lane >= off) incl += u;
    }
    if (lane == 63) wsum[t >> 6] = incl;
    __syncthreads();
    unsigned waveBase = 0;
    int wv = t >> 6;
    for (int i = 0; i < wv; i++) waveBase += wsum[i];
    unsigned excl = blockBase + waveBase + incl - s;
    uint4 a; a.x = w.x; a.y = excl;           a.z = w.y; a.w = excl + p0;
    uint4 b; b.x = w.z; b.y = excl + p0 + p1; b.z = w.w; b.w = excl + p0 + p1 + p2;
    combined4[gw * 2 + 0] = a;
    combined4[gw * 2 + 1] = b;
}

__device__ __forceinline__ unsigned rank_of(unsigned key, const uint2* __restrict__ combined) {
    uint2 cw = combined[key >> 5];
    unsigned bit = key & 31u;
    return cw.y + __popc(cw.x & ((1u << bit) - 1u));
}

// 4) origOf[rank] = original index (4 B scatter)
__global__ void k_scatter_rank(const int4* __restrict__ coords, const uint2* __restrict__ combined,
                               int* __restrict__ origOf, int n) {
    int i = blockIdx.x * blockDim.x + threadIdx.x;
    if (i >= n) return;
    int4 co = coords[i];
    unsigned r = rank_of(make_key(co.x, co.y, co.z, co.w), combined);
    origOf[r] = i;
}

// 5) rank-order gather, float4 clusters: 8 lanes per row, 32 rows/block in flight.
__global__ __launch_bounds__(256) void k_gather_sorted4(const float* __restrict__ feats,
                                                        const int4* __restrict__ coords,
                                                        const int* __restrict__ origOf,
                                                        float* __restrict__ sfeats,
                                                        float* __restrict__ outCoordsF, int n) {
    int t = blockIdx.x * 256 + threadIdx.x;
    int p = t >> 3, q = t & 7;
    if (p >= n) return;
    int o = origOf[p];                                   // broadcast among 8 lanes
    float4 f = ((const float4*)(feats + (size_t)o * NPTS_C))[q]; // scattered 128B row read
    ((float4*)(sfeats + (size_t)p * NPTS_C))[q] = f;     // coalesced write
    if (q == 0) {
        int4 c = coords[o];
        float4 fc; fc.x = (float)c.x; fc.y = (float)c.y; fc.z = (float)c.z; fc.w = (float)c.w;
        ((float4*)outCoordsF)[p] = fc;                   // coords as float VALUES
    }
}

// 6) conv: 4 points per 32-group, center-tap split, float4 cluster gathers.
__global__ __launch_bounds__(256) void k_conv_sorted4(const float* __restrict__ sfeats,
                                                      const float* __restrict__ weight,
                                                      const float* __restrict__ outCoordsF,
                                                      const uint2* __restrict__ combined,
                                                      float* __restrict__ out, int n) {
    __shared__ float4 swT4[NTAPS * 9];   // swT4[kk*9+q] = weights for channels 4q..4q+3, tap kk (pad 8->9)
    __shared__ int ldsN[8][4][28];       // [group][round][tap] resolved sorted rank or -1

    int t = threadIdx.x;
    for (int idx = t; idx < NTAPS * 8; idx += 256) {
        int kk = idx >> 3, q = idx & 7;
        float4 w4;
        w4.x = weight[(4 * q + 0) * NTAPS + kk];
        w4.y = weight[(4 * q + 1) * NTAPS + kk];
        w4.z = weight[(4 * q + 2) * NTAPS + kk];
        w4.w = weight[(4 * q + 3) * NTAPS + kk];
        swT4[kk * 9 + q] = w4;
    }

    int gi = t >> 5, l = t & 31;
    bool hi = (t & 32) != 0;
    int p0 = (blockIdx.x * 8 + gi) * 4;  // 4 consecutive ranks per group
    int cluster = l >> 3, q = l & 7;

    // lane constants (hoisted out of the 4 resolve rounds)
    int dxl = l / 9 - 1, dyl = (l % 9) / 3 - 1, dzl = l % 3 - 1;
    int jl = l / 3;                      // probing lane for tap l
    int pbx = l / 3 - 1, pby = l % 3 - 1; // probe (dx,dy) for lanes 0..8

    unsigned mk[4];
    #pragma unroll
    for (int r = 0; r < 4; r++) {
        int pc = min(p0 + r, n - 1);
        float4 cf = ((const float4*)outCoordsF)[pc]; // broadcast; 4 rounds share one 64B line
        int cb = (int)cf.x, cx = (int)cf.y, cy = (int)cf.z, cz = (int)cf.w;

        uint2 cw; cw.x = 0u; cw.y = 0u;
        if (l < 9) {
            int xj = cx + pbx, yj = cy + pby;
            if ((unsigned)xj < 256u && (unsigned)yj < 256u)
                cw = combined[make_key(cb, xj, yj, cz) >> 5];
        }
        unsigned bb = __shfl(cw.x, jl, 32);
        unsigned pp = __shfl(cw.y, jl, 32);

        int x = cx + dxl, y = cy + dyl, z = cz + dzl;
        int nidx = -1;
        if (l < NTAPS && l != 13 &&
            (unsigned)x < 256u && (unsigned)y < 256u && (unsigned)z < 256u) {
            unsigned keyk = make_key(cb, x, y, z);
            if ((z >> 5) != (cz >> 5)) { // z crossed word boundary: self-probe
                uint2 t2 = combined[keyk >> 5];
                bb = t2.x; pp = t2.y;
            }
            unsigned bit = keyk & 31u;
            if ((bb >> bit) & 1u)
                nidx = (int)(pp + __popc(bb & ((1u << bit) - 1u)));
        }
        unsigned long long bal = __ballot(nidx >= 0);
        mk[r] = hi ? (unsigned)(bal >> 32) : (unsigned)bal;
        if (l < NTAPS) ldsN[gi][r][l] = nidx;
    }
    __syncthreads(); // covers swT4 fill + ldsN writes

    int pm = p0 + cluster;
    float4 acc; acc.x = acc.y = acc.z = acc.w = 0.0f;
    if (pm < n) { // center tap: coalesced row read (512B contiguous per group)
        float4 f = ((const float4*)(sfeats + (size_t)pm * NPTS_C))[q];
        float4 w4 = swT4[13 * 9 + q];
        acc.x = f.x * w4.x; acc.y = f.y * w4.y; acc.z = f.z * w4.z; acc.w = f.w * w4.w;
    }

    unsigned m = mk[cluster]; // cluster-uniform mask, ~0.47 set bits avg
    while (m) {
        int kk = __ffs(m) - 1; m &= m - 1;
        int g = ldsN[gi][cluster][kk];                        // broadcast ds_read
        float4 f = ((const float4*)(sfeats + (size_t)g * NPTS_C))[q]; // scattered 128B row, 4/group in flight
        float4 w4 = swT4[kk * 9 + q];
        acc.x += f.x * w4.x; acc.y += f.y * w4.y; acc.z += f.z * w4.z; acc.w += f.w * w4.w;
    }
    if (pm < n) {
        f32x4 v; v.x = acc.x; v.y = acc.y; v.z = acc.z; v.w = acc.w;
        f32x4* dst = (f32x4*)(out + (size_t)pm * NPTS_C);
        __builtin_nontemporal_store(v, &dst[q]);
    }
}

// ---------------- FALLBACK (small ws) ----------------
__device__ __forceinline__ int resolve_tap(int cb, int cx, int cy, int cz, int k,
                                           const uint2* __restrict__ combined) {
    int dx = k / 9 - 1, dy = (k % 9) / 3 - 1, dz = k % 3 - 1;
    int x = cx + dx, y = cy + dy, z = cz + dz;
    bool valid = (k < NTAPS) && ((unsigned)x < 256u) && ((unsigned)y < 256u) && ((unsigned)z < 256u);
    uint2 cw; cw.x = 0u; cw.y = 0u;
    if (k < 9) {
        int dxj = k / 3 - 1, dyj = k % 3 - 1;
        int xj = cx + dxj, yj = cy + dyj;
        if ((unsigned)xj < 256u && (unsigned)yj < 256u)
            cw = combined[make_key(cb, xj, yj, cz) >> 5];
    }
    int j = k / 3;
    unsigned bb = __shfl(cw.x, j, 32);
    unsigned pp = __shfl(cw.y, j, 32);
    int nidx = -1;
    if (valid) {
        unsigned keyk = make_key(cb, x, y, z);
        if ((z >> 5) != (cz >> 5)) {
            uint2 t2 = combined[keyk >> 5];
            bb = t2.x; pp = t2.y;
        }
        unsigned bit = keyk & 31u;
        if ((bb >> bit) & 1u)
            nidx = (int)(pp + __popc(bb & ((1u << bit) - 1u)));
    }
    return nidx;
}

__global__ __launch_bounds__(256) void k_conv_indirect(const float* __restrict__ feats, const float* __restrict__ weight,
                                                       const int4* __restrict__ coords,
                                                       const uint2* __restrict__ combined,
                                                       const int* __restrict__ origOf,
                                                       float* __restrict__ out, float* __restrict__ outCoordsF, int n) {
    __shared__ float swT[NTAPS * 32];
    for (int idx = threadIdx.x; idx < NTAPS * 32; idx += 256) {
        int kk = idx >> 5, cc = idx & 31;
        swT[idx] = weight[cc * NTAPS + kk];
    }
    __syncthreads();

    int p = blockIdx.x * 8 + (threadIdx.x >> 5);
    int c = threadIdx.x & 31;
    if (p >= n) return;

    int orig = origOf[p];
    int4 co = coords[orig];
    if (c == 0) {
        float4 f; f.x = (float)co.x; f.y = (float)co.y; f.z = (float)co.z; f.w = (float)co.w;
        ((float4*)outCoordsF)[p] = f;
    }

    int nidx0 = resolve_tap(co.x, co.y, co.z, co.w, c, combined);
    int nidx = (nidx0 >= 0) ? origOf[nidx0] : -1;

    unsigned long long full = __ballot(nidx >= 0);
    unsigned mymask = (threadIdx.x & 32) ? (unsigned)(full >> 32) : (unsigned)full;

    float acc = 0.0f;
    while (mymask) {
        int kk = __ffs(mymask) - 1;
        mymask &= mymask - 1;
        int g = __shfl(nidx, kk, 32);
        acc += feats[(size_t)g * NPTS_C + c] * swT[kk * 32 + c];
    }
    out[(size_t)p * NPTS_C + c] = acc;
}

extern "C" void kernel_launch(void* const* d_in, const int* in_sizes, int n_in,
                              void* d_out, int out_size, void* d_ws, size_t ws_size,
                              hipStream_t stream) {
    const float* feats  = (const float*)d_in[0];
    const int4*  coords = (const int4*)d_in[1];
    const float* weight = (const float*)d_in[2];
    const int n = in_sizes[1] / 4;

    float* out        = (float*)d_out;              // [N, 32] f32
    float* outCoordsF = (float*)d_out + n * NPTS_C; // [N, 4] float values

    char* ws = (char*)d_ws;
    unsigned* bitmask   = (unsigned*)ws;                               // 4 MB (reused as origOf)
    uint2*    combined  = (uint2*)(ws + (size_t)KEY_WORDS * 4);        // 8 MB
    unsigned* blockSums = (unsigned*)(ws + (size_t)KEY_WORDS * 12);    // 4 KB
    char*     rest      = ws + (size_t)KEY_WORDS * 12 + 4096;

    int* origOf = (int*)bitmask; // bitmask dead after k_build_combined; N*4 <= 4 MB

    size_t need_big = (size_t)KEY_WORDS * 12 + 4096 + (size_t)n * NPTS_C * 4;
    bool big = ws_size >= need_big;

    (void)hipMemsetAsync(bitmask, 0, (size_t)KEY_WORDS * 4, stream);

    int tb = 256;
    k_scatter_bits<<<(n + tb - 1) / tb, tb, 0, stream>>>(coords, bitmask, n);
    k_popc_sums<<<SCAN_BLOCKS, 256, 0, stream>>>((const uint4*)bitmask, blockSums);
    k_build_combined<<<SCAN_BLOCKS, 256, 0, stream>>>((const uint4*)bitmask, blockSums, (uint4*)combined);
    k_scatter_rank<<<(n + tb - 1) / tb, tb, 0, stream>>>(coords, combined, origOf, n);

    if (big) {
        float* sfeats = (float*)rest; // N*32 f32 = 76.8 MB
        k_gather_sorted4<<<(n + 31) / 32, 256, 0, stream>>>(feats, coords, origOf, sfeats, outCoordsF, n);
        k_conv_sorted4<<<(n + 31) / 32, 256, 0, stream>>>(sfeats, weight, outCoordsF, combined, out, n);
    } else {
        k_conv_indirect<<<(n + 7) / 8, 256, 0, stream>>>(feats, weight, coords, combined, origOf, out, outCoordsF, n);
    }
}